// Round 1
// baseline (334.000 us; speedup 1.0000x reference)
//
#include <hip/hip_runtime.h>

// ---------------------------------------------------------------------------
// MultiHeadAttention: x(2,2048,768) -> QKV proj -> 12-head causal attn -> proj
// Precision: weights split hi/lo bf16 (activations duplicated along K), so
// GEMMs are plain bf16 MFMA with K'=1536; attention bf16 with fp32 softmax.
// ---------------------------------------------------------------------------

typedef float f32x4 __attribute__((ext_vector_type(4)));
typedef __bf16 bf16x8 __attribute__((ext_vector_type(8)));
typedef unsigned short ushort8 __attribute__((ext_vector_type(8)));

#define D_MODEL 768
#define F3 2304
#define NHEADS 12
#define HEAD 64
#define BB 2
#define TT 2048
#define MROWS (BB*TT)      // 4096
#define KSPLIT 1536        // 2*768 (hi/lo interleaved)

__device__ __forceinline__ unsigned short f2bf(float f) {
    unsigned int u = __float_as_uint(f);
    u += 0x7fffu + ((u >> 16) & 1u);
    return (unsigned short)(u >> 16);
}
__device__ __forceinline__ float bf2f(unsigned short h) {
    return __uint_as_float(((unsigned int)h) << 16);
}

__device__ __forceinline__ void async_copy16(unsigned short* lds, const unsigned short* g) {
    __builtin_amdgcn_global_load_lds(
        (const __attribute__((address_space(1))) unsigned int*)(const void*)g,
        (__attribute__((address_space(3))) unsigned int*)(void*)lds,
        16, 0, 0);
}

// ---- prep kernels ---------------------------------------------------------
// x_dup[2*i] = x_dup[2*i+1] = bf16(x[i])  (flat index == (m,2c)/(m,2c+1))
__global__ void dup_act(const float* __restrict__ x, unsigned short* __restrict__ xd, int n) {
    int i = blockIdx.x * blockDim.x + threadIdx.x;
    if (i < n) {
        unsigned short v = f2bf(x[i]);
        xd[2*i] = v; xd[2*i+1] = v;
    }
}
// w_split[2*i] = hi(w[i]), w_split[2*i+1] = lo(w[i])
__global__ void split_w(const float* __restrict__ w, unsigned short* __restrict__ ws, int n) {
    int i = blockIdx.x * blockDim.x + threadIdx.x;
    if (i < n) {
        float f = w[i];
        unsigned short hi = f2bf(f);
        unsigned short lo = f2bf(f - bf2f(hi));
        ws[2*i] = hi; ws[2*i+1] = lo;
    }
}

// ---- GEMM: C[m][n] = sum_k A[m][k] * Bw[n][k] (+bias), both K-major -------
// 128x128 tile, BK=64, 4 waves each 64x64 (4x4 of 16x16x32 MFMA tiles).
// EPI 0: scatter to Q(1/8 scaled)/K/V bf16 (B,H,T,64).  EPI 1: fp32 out.
template<int EPI>
__global__ __launch_bounds__(256, 2) void gemm_bt(
    const unsigned short* __restrict__ A, const unsigned short* __restrict__ Bw,
    const float* __restrict__ bias, int K,
    float* __restrict__ Cout,
    unsigned short* __restrict__ Qb, unsigned short* __restrict__ Kb,
    unsigned short* __restrict__ Vb)
{
    __shared__ unsigned short As[128*64];
    __shared__ unsigned short Bs[128*64];
    const int tid  = threadIdx.x;
    const int wave = tid >> 6;
    const int lane = tid & 63;
    const int quad = lane >> 4;
    const int l16  = lane & 15;
    const int m0 = blockIdx.x * 128;
    const int n0 = blockIdx.y * 128;
    const int wm = (wave >> 1) * 64;
    const int wn = (wave & 1) * 64;

    f32x4 acc[4][4] = {};

    const unsigned short* Ablk = A + (size_t)m0 * K;
    const unsigned short* Bblk = Bw + (size_t)n0 * K;
    const int srow = (lane >> 3);        // 0..7
    const int scol = (lane & 7) * 8;     // element col chunk

    for (int k0 = 0; k0 < K; k0 += 64) {
        #pragma unroll
        for (int q2 = 0; q2 < 4; ++q2) {
            int t = wave * 4 + q2;               // 0..15 -> rows t*8..t*8+7
            int row = t * 8 + srow;
            async_copy16(As + t * 512, Ablk + (size_t)row * K + k0 + scol);
            async_copy16(Bs + t * 512, Bblk + (size_t)row * K + k0 + scol);
        }
        asm volatile("s_waitcnt vmcnt(0)" ::: "memory");
        __syncthreads();

        #pragma unroll
        for (int kc = 0; kc < 64; kc += 32) {
            bf16x8 a[4], b[4];
            #pragma unroll
            for (int i = 0; i < 4; ++i)
                a[i] = *(const bf16x8*)(As + (wm + i*16 + l16)*64 + kc + quad*8);
            #pragma unroll
            for (int j = 0; j < 4; ++j)
                b[j] = *(const bf16x8*)(Bs + (wn + j*16 + l16)*64 + kc + quad*8);
            #pragma unroll
            for (int i = 0; i < 4; ++i)
                #pragma unroll
                for (int j = 0; j < 4; ++j)
                    acc[i][j] = __builtin_amdgcn_mfma_f32_16x16x32_bf16(a[i], b[j], acc[i][j], 0, 0, 0);
        }
        __syncthreads();
    }

    // epilogue: C[m][n], m = m0+wm+i*16+quad*4+r, n = n0+wn+j*16+l16
    #pragma unroll
    for (int j = 0; j < 4; ++j) {
        const int n = n0 + wn + j*16 + l16;
        const float bv = bias[n];
        #pragma unroll
        for (int i = 0; i < 4; ++i) {
            #pragma unroll
            for (int r = 0; r < 4; ++r) {
                const int m = m0 + wm + i*16 + quad*4 + r;
                const float v = acc[i][j][r] + bv;
                if (EPI == 0) {
                    const int b   = m >> 11;          // /2048
                    const int t   = m & 2047;
                    const int seg = n / 768;
                    const int f   = n - seg * 768;
                    const int h   = f >> 6;
                    const int d   = f & 63;
                    const size_t idx = (((size_t)(b * NHEADS + h)) * TT + t) * HEAD + d;
                    if (seg == 0)      Qb[idx] = f2bf(v * 0.125f);  // fold 1/sqrt(64)
                    else if (seg == 1) Kb[idx] = f2bf(v);
                    else               Vb[idx] = f2bf(v);
                } else {
                    Cout[(size_t)m * D_MODEL + n] = v;
                }
            }
        }
    }
}

// ---- flash attention (causal) ---------------------------------------------
// grid (32, 24): blockIdx.x = q-tile (BQ=64), blockIdx.y = b*12+h.
// 4 waves; wave w handles q-rows [w*16, w*16+16). KV tiles of 128.
__global__ __launch_bounds__(256, 2) void attn(
    const unsigned short* __restrict__ Qb, const unsigned short* __restrict__ Kb,
    const unsigned short* __restrict__ Vb, unsigned short* __restrict__ Odup)
{
    __shared__ unsigned short Qs[64*64];
    __shared__ unsigned short Ks[128*64];
    __shared__ unsigned short Vt[64*128];      // transposed: [d][k]
    __shared__ unsigned short Ps[4][16*128];   // per-wave P tile

    const int tid  = threadIdx.x;
    const int wave = tid >> 6;
    const int lane = tid & 63;
    const int quad = lane >> 4;
    const int l16  = lane & 15;
    const int qt = blockIdx.x;
    const int bh = blockIdx.y;
    const size_t hbase = (size_t)bh * TT * HEAD;

    {   // Q tile: 64x64 bf16 = 8KB = 512 uint4
        const uint4* src = (const uint4*)(Qb + hbase + (size_t)qt * 64 * HEAD);
        uint4* dst = (uint4*)Qs;
        for (int i = tid; i < 512; i += 256) dst[i] = src[i];
    }

    f32x4 oacc[4] = {};
    float mst[4] = {-1e30f, -1e30f, -1e30f, -1e30f};
    float lst[4] = {0.f, 0.f, 0.f, 0.f};
    const int nkt = (qt >> 1) + 1;

    for (int kt = 0; kt < nkt; ++kt) {
        __syncthreads();   // prev consumers done (first iter: Qs visible)
        {   // K tile 128x64 = 1024 uint4
            const uint4* src = (const uint4*)(Kb + hbase + (size_t)kt * 128 * HEAD);
            uint4* dst = (uint4*)Ks;
            for (int i = tid; i < 1024; i += 256) dst[i] = src[i];
        }
        {   // V tile transposed into Vt[d][k]
            const int kk = tid >> 1, d0 = (tid & 1) * 32;
            const unsigned short* vrow = Vb + hbase + (size_t)(kt * 128 + kk) * HEAD + d0;
            #pragma unroll
            for (int c = 0; c < 4; ++c) {
                ushort8 v = *(const ushort8*)(vrow + c * 8);
                #pragma unroll
                for (int jj = 0; jj < 8; ++jj) Vt[(d0 + c*8 + jj) * 128 + kk] = v[jj];
            }
        }
        __syncthreads();

        // S = Q K^T : wave's 16 rows x 128 cols
        f32x4 s[8] = {};
        #pragma unroll
        for (int kc = 0; kc < 64; kc += 32) {
            bf16x8 aq = *(const bf16x8*)(Qs + (wave*16 + l16)*64 + kc + quad*8);
            #pragma unroll
            for (int nt = 0; nt < 8; ++nt) {
                bf16x8 bk = *(const bf16x8*)(Ks + (nt*16 + l16)*64 + kc + quad*8);
                s[nt] = __builtin_amdgcn_mfma_f32_16x16x32_bf16(aq, bk, s[nt], 0, 0, 0);
            }
        }

        // causal mask + row max
        const int qrow0 = qt*64 + wave*16 + quad*4;   // +r = global q row
        float mloc[4] = {-1e30f, -1e30f, -1e30f, -1e30f};
        #pragma unroll
        for (int nt = 0; nt < 8; ++nt) {
            const int kg = kt*128 + nt*16 + l16;
            #pragma unroll
            for (int r = 0; r < 4; ++r) {
                float v = s[nt][r];
                v = (kg > qrow0 + r) ? -1e30f : v;
                s[nt][r] = v;
                mloc[r] = fmaxf(mloc[r], v);
            }
        }
        #pragma unroll
        for (int r = 0; r < 4; ++r) {
            #pragma unroll
            for (int off = 1; off < 16; off <<= 1)
                mloc[r] = fmaxf(mloc[r], __shfl_xor(mloc[r], off));
        }
        float alpha[4], rsum[4];
        #pragma unroll
        for (int r = 0; r < 4; ++r) {
            const float mnew = fmaxf(mst[r], mloc[r]);
            alpha[r] = exp2f((mst[r] - mnew) * 1.44269504f);
            mst[r] = mnew;
            rsum[r] = 0.f;
        }
        // P = exp(s - m), store bf16 to LDS (A-operand layout source)
        #pragma unroll
        for (int nt = 0; nt < 8; ++nt) {
            #pragma unroll
            for (int r = 0; r < 4; ++r) {
                const float p = exp2f((s[nt][r] - mst[r]) * 1.44269504f);
                rsum[r] += p;
                Ps[wave][(quad*4 + r)*128 + nt*16 + l16] = f2bf(p);
            }
        }
        #pragma unroll
        for (int r = 0; r < 4; ++r) {
            #pragma unroll
            for (int off = 1; off < 16; off <<= 1)
                rsum[r] += __shfl_xor(rsum[r], off);
            lst[r] = lst[r] * alpha[r] + rsum[r];
        }
        #pragma unroll
        for (int dt = 0; dt < 4; ++dt)
            #pragma unroll
            for (int r = 0; r < 4; ++r)
                oacc[dt][r] *= alpha[r];

        // O += P V   (A from Ps[wave], B from Vt)
        #pragma unroll
        for (int kc = 0; kc < 4; ++kc) {
            bf16x8 ap = *(const bf16x8*)(&Ps[wave][l16*128 + kc*32 + quad*8]);
            #pragma unroll
            for (int dt = 0; dt < 4; ++dt) {
                bf16x8 bv = *(const bf16x8*)(Vt + (dt*16 + l16)*128 + kc*32 + quad*8);
                oacc[dt] = __builtin_amdgcn_mfma_f32_16x16x32_bf16(ap, bv, oacc[dt], 0, 0, 0);
            }
        }
    }

    // epilogue: O/l -> Odup (4096 x 1536, duplicated cols for hi/lo GEMM2)
    const int b = bh / NHEADS, h = bh % NHEADS;
    #pragma unroll
    for (int r = 0; r < 4; ++r) {
        const float inv = 1.0f / lst[r];
        const int m = b * TT + qt*64 + wave*16 + quad*4 + r;
        #pragma unroll
        for (int dt = 0; dt < 4; ++dt) {
            const unsigned short ob = f2bf(oacc[dt][r] * inv);
            const size_t o0 = (size_t)m * KSPLIT + (size_t)(h*HEAD + dt*16 + l16) * 2;
            Odup[o0] = ob; Odup[o0 + 1] = ob;
        }
    }
}

// ---------------------------------------------------------------------------
extern "C" void kernel_launch(void* const* d_in, const int* in_sizes, int n_in,
                              void* d_out, int out_size, void* d_ws, size_t ws_size,
                              hipStream_t stream) {
    const float* x  = (const float*)d_in[0];
    const float* W1 = (const float*)d_in[1];
    const float* b1 = (const float*)d_in[2];
    const float* W2 = (const float*)d_in[3];
    const float* b2 = (const float*)d_in[4];
    float* out = (float*)d_out;

    unsigned short* ws = (unsigned short*)d_ws;
    unsigned short* xdup = ws;                                  // 4096*1536
    unsigned short* w1s  = xdup + (size_t)MROWS * KSPLIT;       // 2304*1536
    unsigned short* w2s  = w1s + (size_t)F3 * KSPLIT;           // 768*1536
    unsigned short* Qb   = w2s + (size_t)D_MODEL * KSPLIT;      // 24*2048*64
    unsigned short* Kb   = Qb + (size_t)BB*NHEADS*TT*HEAD;
    unsigned short* Vb   = Kb + (size_t)BB*NHEADS*TT*HEAD;
    unsigned short* Odup = Vb + (size_t)BB*NHEADS*TT*HEAD;      // 4096*1536

    dup_act<<<(MROWS*D_MODEL + 255)/256, 256, 0, stream>>>(x, xdup, MROWS*D_MODEL);
    split_w<<<(F3*D_MODEL + 255)/256, 256, 0, stream>>>(W1, w1s, F3*D_MODEL);
    split_w<<<(D_MODEL*D_MODEL + 255)/256, 256, 0, stream>>>(W2, w2s, D_MODEL*D_MODEL);

    gemm_bt<0><<<dim3(MROWS/128, F3/128), 256, 0, stream>>>(
        xdup, w1s, b1, KSPLIT, nullptr, Qb, Kb, Vb);

    attn<<<dim3(TT/64, BB*NHEADS), 256, 0, stream>>>(Qb, Kb, Vb, Odup);

    gemm_bt<1><<<dim3(MROWS/128, D_MODEL/128), 256, 0, stream>>>(
        Odup, w2s, b2, KSPLIT, out, nullptr, nullptr, nullptr);
}

// Round 2
// 266.169 us; speedup vs baseline: 1.2548x; 1.2548x over previous
//
#include <hip/hip_runtime.h>

// ---------------------------------------------------------------------------
// MultiHeadAttention: x(2,2048,768) -> QKV proj -> 12-head causal attn -> proj
// Precision: weights split hi/lo bf16 (activations duplicated along K), so
// GEMMs are plain bf16 MFMA with K'=1536; attention bf16 with fp32 softmax.
// Round 2: attn rewritten around S^T = K Q^T so P-store is b64-packed
// (conflict-free), V-transpose is b64-packed, softmax reductions are 2
// shuffles, K/Q staged via global_load_lds.
// ---------------------------------------------------------------------------

typedef float f32x4 __attribute__((ext_vector_type(4)));
typedef __bf16 bf16x8 __attribute__((ext_vector_type(8)));
typedef unsigned short ushort8 __attribute__((ext_vector_type(8)));
typedef unsigned short ushort4v __attribute__((ext_vector_type(4)));

#define D_MODEL 768
#define F3 2304
#define NHEADS 12
#define HEAD 64
#define BB 2
#define TT 2048
#define MROWS (BB*TT)      // 4096
#define KSPLIT 1536        // 2*768 (hi/lo interleaved)
#define LOG2E 1.44269504f

__device__ __forceinline__ unsigned short f2bf(float f) {
    unsigned int u = __float_as_uint(f);
    u += 0x7fffu + ((u >> 16) & 1u);
    return (unsigned short)(u >> 16);
}
__device__ __forceinline__ float bf2f(unsigned short h) {
    return __uint_as_float(((unsigned int)h) << 16);
}
// RNE-pack two f32 into bf16x2 (lo in low half)
__device__ __forceinline__ unsigned int pack2bf(float a, float b) {
    unsigned int ua = __float_as_uint(a), ub = __float_as_uint(b);
    ua += 0x7fffu + ((ua >> 16) & 1u);
    ub += 0x7fffu + ((ub >> 16) & 1u);
    return (ua >> 16) | (ub & 0xffff0000u);
}

__device__ __forceinline__ void async_copy16(unsigned short* lds, const unsigned short* g) {
    __builtin_amdgcn_global_load_lds(
        (const __attribute__((address_space(1))) unsigned int*)(const void*)g,
        (__attribute__((address_space(3))) unsigned int*)(void*)lds,
        16, 0, 0);
}

// ---- prep kernels ---------------------------------------------------------
__global__ void dup_act(const float* __restrict__ x, unsigned short* __restrict__ xd, int n) {
    int i = blockIdx.x * blockDim.x + threadIdx.x;
    if (i < n) {
        unsigned short v = f2bf(x[i]);
        xd[2*i] = v; xd[2*i+1] = v;
    }
}
__global__ void split_w(const float* __restrict__ w, unsigned short* __restrict__ ws, int n) {
    int i = blockIdx.x * blockDim.x + threadIdx.x;
    if (i < n) {
        float f = w[i];
        unsigned short hi = f2bf(f);
        unsigned short lo = f2bf(f - bf2f(hi));
        ws[2*i] = hi; ws[2*i+1] = lo;
    }
}

// ---- GEMM: C[m][n] = sum_k A[m][k] * Bw[n][k] (+bias), both K-major -------
template<int EPI>
__global__ __launch_bounds__(256, 2) void gemm_bt(
    const unsigned short* __restrict__ A, const unsigned short* __restrict__ Bw,
    const float* __restrict__ bias, int K,
    float* __restrict__ Cout,
    unsigned short* __restrict__ Qb, unsigned short* __restrict__ Kb,
    unsigned short* __restrict__ Vb)
{
    __shared__ unsigned short As[128*64];
    __shared__ unsigned short Bs[128*64];
    const int tid  = threadIdx.x;
    const int wave = tid >> 6;
    const int lane = tid & 63;
    const int quad = lane >> 4;
    const int l16  = lane & 15;
    const int m0 = blockIdx.x * 128;
    const int n0 = blockIdx.y * 128;
    const int wm = (wave >> 1) * 64;
    const int wn = (wave & 1) * 64;

    f32x4 acc[4][4] = {};

    const unsigned short* Ablk = A + (size_t)m0 * K;
    const unsigned short* Bblk = Bw + (size_t)n0 * K;
    const int srow = (lane >> 3);
    const int scol = (lane & 7) * 8;

    for (int k0 = 0; k0 < K; k0 += 64) {
        #pragma unroll
        for (int q2 = 0; q2 < 4; ++q2) {
            int t = wave * 4 + q2;
            int row = t * 8 + srow;
            async_copy16(As + t * 512, Ablk + (size_t)row * K + k0 + scol);
            async_copy16(Bs + t * 512, Bblk + (size_t)row * K + k0 + scol);
        }
        asm volatile("s_waitcnt vmcnt(0)" ::: "memory");
        __syncthreads();

        #pragma unroll
        for (int kc = 0; kc < 64; kc += 32) {
            bf16x8 a[4], b[4];
            #pragma unroll
            for (int i = 0; i < 4; ++i)
                a[i] = *(const bf16x8*)(As + (wm + i*16 + l16)*64 + kc + quad*8);
            #pragma unroll
            for (int j = 0; j < 4; ++j)
                b[j] = *(const bf16x8*)(Bs + (wn + j*16 + l16)*64 + kc + quad*8);
            #pragma unroll
            for (int i = 0; i < 4; ++i)
                #pragma unroll
                for (int j = 0; j < 4; ++j)
                    acc[i][j] = __builtin_amdgcn_mfma_f32_16x16x32_bf16(a[i], b[j], acc[i][j], 0, 0, 0);
        }
        __syncthreads();
    }

    #pragma unroll
    for (int j = 0; j < 4; ++j) {
        const int n = n0 + wn + j*16 + l16;
        const float bv = bias[n];
        #pragma unroll
        for (int i = 0; i < 4; ++i) {
            #pragma unroll
            for (int r = 0; r < 4; ++r) {
                const int m = m0 + wm + i*16 + quad*4 + r;
                const float v = acc[i][j][r] + bv;
                if (EPI == 0) {
                    const int b   = m >> 11;
                    const int t   = m & 2047;
                    const int seg = n / 768;
                    const int f   = n - seg * 768;
                    const int h   = f >> 6;
                    const int d   = f & 63;
                    const size_t idx = (((size_t)(b * NHEADS + h)) * TT + t) * HEAD + d;
                    if (seg == 0)      Qb[idx] = f2bf(v * 0.125f);  // fold 1/sqrt(64)
                    else if (seg == 1) Kb[idx] = f2bf(v);
                    else               Vb[idx] = f2bf(v);
                } else {
                    Cout[(size_t)m * D_MODEL + n] = v;
                }
            }
        }
    }
}

// ---- flash attention (causal), S^T formulation ----------------------------
// grid (32, 24): qt = 31 - blockIdx.x (heavy blocks first), bh = blockIdx.y.
// 4 waves; wave w owns q-rows [w*16, w*16+16). KV tiles of 128.
// S^T = K Q^T: C-layout -> lane l16 = q, quad*4+r = k. Softmax state is
// per-lane (q = l16); P written b64-packed to Ps[q][k] (stride 136);
// V transposed b64-packed into Vt[d][k] (stride 132).
#define VSTR 132
#define PSTR 136
__global__ __launch_bounds__(256, 2) void attn(
    const unsigned short* __restrict__ Qb, const unsigned short* __restrict__ Kb,
    const unsigned short* __restrict__ Vb, unsigned short* __restrict__ Odup)
{
    __shared__ unsigned short Qs[64*64];
    __shared__ unsigned short Ks[128*64];
    __shared__ unsigned short Vt[64*VSTR];
    __shared__ unsigned short Ps[4][16*PSTR];

    const int tid  = threadIdx.x;
    const int wave = tid >> 6;
    const int lane = tid & 63;
    const int quad = lane >> 4;
    const int l16  = lane & 15;
    const int qt = gridDim.x - 1 - blockIdx.x;
    const int bh = blockIdx.y;
    const size_t hbase = (size_t)bh * TT * HEAD;

    // stage Q (async, contiguous)
    {
        const unsigned short* qsrc = Qb + hbase + (size_t)qt * 64 * HEAD;
        async_copy16(Qs + tid*8, qsrc + tid*8);
        async_copy16(Qs + (256+tid)*8, qsrc + (256+tid)*8);
    }

    f32x4 oacc[4] = {};
    float mst = -1e30f, lst = 0.f;
    const int nkt = (qt >> 1) + 1;
    const int qg = qt*64 + wave*16 + l16;    // this lane's global q row

    for (int kt = 0; kt < nkt; ++kt) {
        __syncthreads();   // prev iteration's consumers done with Ks/Vt

        // K tile async (contiguous 16KB)
        const unsigned short* ksrc = Kb + hbase + (size_t)kt * 128 * HEAD;
        #pragma unroll
        for (int i = 0; i < 4; ++i)
            async_copy16(Ks + (i*256 + tid)*8, ksrc + (i*256 + tid)*8);

        // V tile -> Vt[d][k] transposed, b64-packed (4 k per write)
        {
            const int kk4 = (tid & 31) * 4;       // 0..124
            const int d0  = (tid >> 5) * 8;       // 0..56
            const unsigned short* vsrc = Vb + hbase + (size_t)(kt*128 + kk4)*HEAD + d0;
            ushort8 vr0 = *(const ushort8*)(vsrc);
            ushort8 vr1 = *(const ushort8*)(vsrc + HEAD);
            ushort8 vr2 = *(const ushort8*)(vsrc + 2*HEAD);
            ushort8 vr3 = *(const ushort8*)(vsrc + 3*HEAD);
            #pragma unroll
            for (int j = 0; j < 8; ++j) {
                ushort4v pk;
                pk.x = vr0[j]; pk.y = vr1[j]; pk.z = vr2[j]; pk.w = vr3[j];
                *(ushort4v*)(&Vt[(d0 + j)*VSTR + kk4]) = pk;
            }
        }
        asm volatile("s_waitcnt vmcnt(0)" ::: "memory");
        __syncthreads();

        // S^T = K Q^T : rows k (128), cols q (wave's 16)
        f32x4 s[8] = {};
        #pragma unroll
        for (int kc = 0; kc < 64; kc += 32) {
            bf16x8 bq = *(const bf16x8*)(Qs + (wave*16 + l16)*64 + kc + quad*8);
            #pragma unroll
            for (int nt = 0; nt < 8; ++nt) {
                bf16x8 ak = *(const bf16x8*)(Ks + (nt*16 + l16)*64 + kc + quad*8);
                s[nt] = __builtin_amdgcn_mfma_f32_16x16x32_bf16(ak, bq, s[nt], 0, 0, 0);
            }
        }

        // causal mask: only the last KV tile straddles the diagonal
        if (kt == nkt - 1) {
            const int kq = kt*128 + quad*4;
            #pragma unroll
            for (int nt = 0; nt < 8; ++nt)
                #pragma unroll
                for (int r = 0; r < 4; ++r)
                    if (kq + nt*16 + r > qg) s[nt][r] = -1e30f;
        }

        // online softmax (per-lane state, q = l16)
        float mloc = -1e30f;
        #pragma unroll
        for (int nt = 0; nt < 8; ++nt)
            #pragma unroll
            for (int r = 0; r < 4; ++r)
                mloc = fmaxf(mloc, s[nt][r]);
        mloc = fmaxf(mloc, __shfl_xor(mloc, 16));
        mloc = fmaxf(mloc, __shfl_xor(mloc, 32));
        const float mnew = fmaxf(mst, mloc);
        const float alpha = exp2f((mst - mnew) * LOG2E);
        const float mc = mnew * LOG2E;
        mst = mnew;

        float rsum = 0.f;
        uint2 pck[8];
        #pragma unroll
        for (int nt = 0; nt < 8; ++nt) {
            const float p0 = exp2f(s[nt][0]*LOG2E - mc);
            const float p1 = exp2f(s[nt][1]*LOG2E - mc);
            const float p2 = exp2f(s[nt][2]*LOG2E - mc);
            const float p3 = exp2f(s[nt][3]*LOG2E - mc);
            rsum += (p0 + p1) + (p2 + p3);
            pck[nt].x = pack2bf(p0, p1);
            pck[nt].y = pack2bf(p2, p3);
        }
        rsum += __shfl_xor(rsum, 16);
        rsum += __shfl_xor(rsum, 32);
        lst = lst * alpha + rsum;

        // P[q][k] b64-packed (4 consecutive k = quad*4+r of tile nt)
        #pragma unroll
        for (int nt = 0; nt < 8; ++nt)
            *(uint2*)(&Ps[wave][l16*PSTR + nt*16 + quad*4]) = pck[nt];

        // rescale O by alpha (per q row = quad*4+r)
        float af[4];
        #pragma unroll
        for (int r = 0; r < 4; ++r) af[r] = __shfl(alpha, quad*4 + r);
        #pragma unroll
        for (int dt = 0; dt < 4; ++dt)
            #pragma unroll
            for (int r = 0; r < 4; ++r)
                oacc[dt][r] *= af[r];

        // O += P V  (A = P[q][k], B = Vt[d][k])
        #pragma unroll
        for (int kc = 0; kc < 4; ++kc) {
            bf16x8 ap = *(const bf16x8*)(&Ps[wave][l16*PSTR + kc*32 + quad*8]);
            #pragma unroll
            for (int dt = 0; dt < 4; ++dt) {
                bf16x8 bv = *(const bf16x8*)(Vt + (dt*16 + l16)*VSTR + kc*32 + quad*8);
                oacc[dt] = __builtin_amdgcn_mfma_f32_16x16x32_bf16(ap, bv, oacc[dt], 0, 0, 0);
            }
        }
    }

    // epilogue: O/l -> Odup (4096 x 1536, duplicated cols for hi/lo GEMM2)
    const float linv = 1.0f / lst;
    float lr[4];
    #pragma unroll
    for (int r = 0; r < 4; ++r) lr[r] = __shfl(linv, quad*4 + r);
    const int b = bh / NHEADS, h = bh % NHEADS;
    #pragma unroll
    for (int r = 0; r < 4; ++r) {
        const int m = b * TT + qt*64 + wave*16 + quad*4 + r;
        #pragma unroll
        for (int dt = 0; dt < 4; ++dt) {
            const unsigned short ob = f2bf(oacc[dt][r] * lr[r]);
            const size_t o0 = (size_t)m * KSPLIT + (size_t)(h*HEAD + dt*16 + l16) * 2;
            Odup[o0] = ob; Odup[o0 + 1] = ob;
        }
    }
}

// ---------------------------------------------------------------------------
extern "C" void kernel_launch(void* const* d_in, const int* in_sizes, int n_in,
                              void* d_out, int out_size, void* d_ws, size_t ws_size,
                              hipStream_t stream) {
    const float* x  = (const float*)d_in[0];
    const float* W1 = (const float*)d_in[1];
    const float* b1 = (const float*)d_in[2];
    const float* W2 = (const float*)d_in[3];
    const float* b2 = (const float*)d_in[4];
    float* out = (float*)d_out;

    unsigned short* ws = (unsigned short*)d_ws;
    unsigned short* xdup = ws;                                  // 4096*1536
    unsigned short* w1s  = xdup + (size_t)MROWS * KSPLIT;       // 2304*1536
    unsigned short* w2s  = w1s + (size_t)F3 * KSPLIT;           // 768*1536
    unsigned short* Qb   = w2s + (size_t)D_MODEL * KSPLIT;      // 24*2048*64
    unsigned short* Kb   = Qb + (size_t)BB*NHEADS*TT*HEAD;
    unsigned short* Vb   = Kb + (size_t)BB*NHEADS*TT*HEAD;
    unsigned short* Odup = Vb + (size_t)BB*NHEADS*TT*HEAD;      // 4096*1536

    dup_act<<<(MROWS*D_MODEL + 255)/256, 256, 0, stream>>>(x, xdup, MROWS*D_MODEL);
    split_w<<<(F3*D_MODEL + 255)/256, 256, 0, stream>>>(W1, w1s, F3*D_MODEL);
    split_w<<<(D_MODEL*D_MODEL + 255)/256, 256, 0, stream>>>(W2, w2s, D_MODEL*D_MODEL);

    gemm_bt<0><<<dim3(MROWS/128, F3/128), 256, 0, stream>>>(
        xdup, w1s, b1, KSPLIT, nullptr, Qb, Kb, Vb);

    attn<<<dim3(TT/64, BB*NHEADS), 256, 0, stream>>>(Qb, Kb, Vb, Odup);

    gemm_bt<1><<<dim3(MROWS/128, D_MODEL/128), 256, 0, stream>>>(
        Odup, w2s, b2, KSPLIT, out, nullptr, nullptr, nullptr);
}

// Round 5
// 260.949 us; speedup vs baseline: 1.2799x; 1.0200x over previous
//
#include <hip/hip_runtime.h>

// ---------------------------------------------------------------------------
// MultiHeadAttention: x(2,2048,768) -> QKV proj -> 12-head causal attn -> proj
// Precision: weights split hi/lo bf16 (activations duplicated along K), so
// GEMMs are plain bf16 MFMA with K'=1536; attention bf16 with fp32 softmax.
// Round 4: round-3 design, defensive resubmit. V^T precomputed once (vtrans);
// attn stages K and V^T via coalesced global_load_lds; Q in registers; 49 KB
// LDS -> 3 blocks/CU (LDS-limited; launch_bounds(256,2) is enough).
// ---------------------------------------------------------------------------

typedef float f32x4 __attribute__((ext_vector_type(4)));
typedef __bf16 bf16x8 __attribute__((ext_vector_type(8)));
typedef unsigned short ushort8 __attribute__((ext_vector_type(8)));
typedef unsigned short ushort4v __attribute__((ext_vector_type(4)));

#define D_MODEL 768
#define F3 2304
#define NHEADS 12
#define HEAD 64
#define BB 2
#define TT 2048
#define MROWS (BB*TT)      // 4096
#define KSPLIT 1536        // 2*768 (hi/lo interleaved)
#define LOG2E 1.44269504f

__device__ __forceinline__ unsigned short f2bf(float f) {
    unsigned int u = __float_as_uint(f);
    u += 0x7fffu + ((u >> 16) & 1u);
    return (unsigned short)(u >> 16);
}
__device__ __forceinline__ float bf2f(unsigned short h) {
    return __uint_as_float(((unsigned int)h) << 16);
}
__device__ __forceinline__ unsigned int pack2bf(float a, float b) {
    unsigned int ua = __float_as_uint(a), ub = __float_as_uint(b);
    ua += 0x7fffu + ((ua >> 16) & 1u);
    ub += 0x7fffu + ((ub >> 16) & 1u);
    return (ua >> 16) | (ub & 0xffff0000u);
}

__device__ __forceinline__ void async_copy16(unsigned short* lds, const unsigned short* g) {
    __builtin_amdgcn_global_load_lds(
        (const __attribute__((address_space(1))) unsigned int*)(const void*)g,
        (__attribute__((address_space(3))) unsigned int*)(void*)lds,
        16, 0, 0);
}

// ---- prep kernels ---------------------------------------------------------
__global__ void dup_act(const float* __restrict__ x, unsigned short* __restrict__ xd, int n) {
    int i = blockIdx.x * blockDim.x + threadIdx.x;
    if (i < n) {
        unsigned short v = f2bf(x[i]);
        xd[2*i] = v; xd[2*i+1] = v;
    }
}
__global__ void split_w(const float* __restrict__ w, unsigned short* __restrict__ ws, int n) {
    int i = blockIdx.x * blockDim.x + threadIdx.x;
    if (i < n) {
        float f = w[i];
        unsigned short hi = f2bf(f);
        unsigned short lo = f2bf(f - bf2f(hi));
        ws[2*i] = hi; ws[2*i+1] = lo;
    }
}

// ---- V transpose: Vb (bh, t, d) -> VT (bh, d, t) --------------------------
__global__ void vtrans(const unsigned short* __restrict__ Vb,
                       unsigned short* __restrict__ VT) {
    __shared__ unsigned short Vs[64 * 68];
    const int tid = threadIdx.x;
    const int bx = blockIdx.x, bh = blockIdx.y;
    const size_t base = (size_t)bh * TT * HEAD + (size_t)bx * 64 * HEAD;

    {   // load 64x64 tile: thread -> row t=tid/4, cols dblk..dblk+15
        const int t = tid >> 2, dblk = (tid & 3) * 16;
        const unsigned short* src = Vb + base + t * HEAD + dblk;
        ushort4v a = *(const ushort4v*)(src);
        ushort4v b = *(const ushort4v*)(src + 4);
        ushort4v c = *(const ushort4v*)(src + 8);
        ushort4v d = *(const ushort4v*)(src + 12);
        unsigned short* dst = &Vs[t * 68 + dblk];
        *(ushort4v*)(dst)      = a;
        *(ushort4v*)(dst + 4)  = b;
        *(ushort4v*)(dst + 8)  = c;
        *(ushort4v*)(dst + 12) = d;
    }
    __syncthreads();
    {   // store: thread -> col d=tid/4, rows t4*16..t4*16+15
        const int d = tid >> 2, t4 = tid & 3;
        ushort8 o0, o1;
        #pragma unroll
        for (int k = 0; k < 8; ++k) o0[k] = Vs[(t4*16 + k) * 68 + d];
        #pragma unroll
        for (int k = 0; k < 8; ++k) o1[k] = Vs[(t4*16 + 8 + k) * 68 + d];
        unsigned short* dst = VT + (size_t)bh * HEAD * TT + (size_t)d * TT + bx * 64 + t4 * 16;
        *(ushort8*)dst = o0;
        *(ushort8*)(dst + 8) = o1;
    }
}

// ---- GEMM: C[m][n] = sum_k A[m][k] * Bw[n][k] (+bias), both K-major -------
template<int EPI>
__global__ __launch_bounds__(256, 2) void gemm_bt(
    const unsigned short* __restrict__ A, const unsigned short* __restrict__ Bw,
    const float* __restrict__ bias, int K,
    float* __restrict__ Cout,
    unsigned short* __restrict__ Qb, unsigned short* __restrict__ Kb,
    unsigned short* __restrict__ Vb)
{
    __shared__ unsigned short As[128*64];
    __shared__ unsigned short Bs[128*64];
    const int tid  = threadIdx.x;
    const int wave = tid >> 6;
    const int lane = tid & 63;
    const int quad = lane >> 4;
    const int l16  = lane & 15;
    const int m0 = blockIdx.x * 128;
    const int n0 = blockIdx.y * 128;
    const int wm = (wave >> 1) * 64;
    const int wn = (wave & 1) * 64;

    f32x4 acc[4][4] = {};

    const unsigned short* Ablk = A + (size_t)m0 * K;
    const unsigned short* Bblk = Bw + (size_t)n0 * K;
    const int srow = (lane >> 3);
    const int scol = (lane & 7) * 8;

    for (int k0 = 0; k0 < K; k0 += 64) {
        #pragma unroll
        for (int q2 = 0; q2 < 4; ++q2) {
            int t = wave * 4 + q2;
            int row = t * 8 + srow;
            async_copy16(As + t * 512, Ablk + (size_t)row * K + k0 + scol);
            async_copy16(Bs + t * 512, Bblk + (size_t)row * K + k0 + scol);
        }
        asm volatile("s_waitcnt vmcnt(0)" ::: "memory");
        __syncthreads();

        #pragma unroll
        for (int kc = 0; kc < 64; kc += 32) {
            bf16x8 a[4], b[4];
            #pragma unroll
            for (int i = 0; i < 4; ++i)
                a[i] = *(const bf16x8*)(As + (wm + i*16 + l16)*64 + kc + quad*8);
            #pragma unroll
            for (int j = 0; j < 4; ++j)
                b[j] = *(const bf16x8*)(Bs + (wn + j*16 + l16)*64 + kc + quad*8);
            #pragma unroll
            for (int i = 0; i < 4; ++i)
                #pragma unroll
                for (int j = 0; j < 4; ++j)
                    acc[i][j] = __builtin_amdgcn_mfma_f32_16x16x32_bf16(a[i], b[j], acc[i][j], 0, 0, 0);
        }
        __syncthreads();
    }

    #pragma unroll
    for (int j = 0; j < 4; ++j) {
        const int n = n0 + wn + j*16 + l16;
        const float bv = bias[n];
        #pragma unroll
        for (int i = 0; i < 4; ++i) {
            #pragma unroll
            for (int r = 0; r < 4; ++r) {
                const int m = m0 + wm + i*16 + quad*4 + r;
                const float v = acc[i][j][r] + bv;
                if (EPI == 0) {
                    const int b   = m >> 11;
                    const int t   = m & 2047;
                    const int seg = n / 768;
                    const int f   = n - seg * 768;
                    const int h   = f >> 6;
                    const int d   = f & 63;
                    const size_t idx = (((size_t)(b * NHEADS + h)) * TT + t) * HEAD + d;
                    if (seg == 0)      Qb[idx] = f2bf(v * 0.125f);  // fold 1/sqrt(64)
                    else if (seg == 1) Kb[idx] = f2bf(v);
                    else               Vb[idx] = f2bf(v);
                } else {
                    Cout[(size_t)m * D_MODEL + n] = v;
                }
            }
        }
    }
}

// ---- flash attention (causal), S^T formulation ----------------------------
// grid (32, 24): qt = 31 - blockIdx.x (heavy first), bh = blockIdx.y.
// S^T = K Q^T: C-layout -> l16 = q, quad*4+r = k. Q in registers; K and V^T
// staged via coalesced global_load_lds; P round-trips LDS (stride 136).
// 49 KB LDS -> 3 blocks/CU (LDS-limited; VGPR ~110 permits it at (256,2)).
#define PSTR 136
__global__ __launch_bounds__(256, 2) void attn(
    const unsigned short* __restrict__ Qb, const unsigned short* __restrict__ Kb,
    const unsigned short* __restrict__ VT, unsigned short* __restrict__ Odup)
{
    __shared__ unsigned short Ks[128*64];
    __shared__ unsigned short Vt[64*128];
    __shared__ unsigned short Ps[4][16*PSTR];

    const int tid  = threadIdx.x;
    const int wave = tid >> 6;
    const int lane = tid & 63;
    const int quad = lane >> 4;
    const int l16  = lane & 15;
    const int qt = gridDim.x - 1 - blockIdx.x;
    const int bh = blockIdx.y;
    const size_t hbase = (size_t)bh * TT * HEAD;
    const int qg = qt*64 + wave*16 + l16;    // this lane's global q row

    // Q fragment in registers (B-operand: lane l16 = q row, 2 k-slices)
    bf16x8 qreg[2];
    {
        const unsigned short* qp = Qb + hbase + (size_t)qg * HEAD + quad*8;
        qreg[0] = *(const bf16x8*)(qp);
        qreg[1] = *(const bf16x8*)(qp + 32);
    }

    f32x4 oacc[4] = {};
    float mst = -1e30f, lst = 0.f;
    const int nkt = (qt >> 1) + 1;

    for (int kt = 0; kt < nkt; ++kt) {
        __syncthreads();   // prev iteration's consumers done with Ks/Vt

        // K tile async (contiguous 16KB)
        const unsigned short* ksrc = Kb + hbase + (size_t)kt * 128 * HEAD;
        #pragma unroll
        for (int i = 0; i < 4; ++i)
            async_copy16(Ks + (i*256 + tid)*8, ksrc + (i*256 + tid)*8);

        // V^T tile async: LDS Vt[d][128], global rows VT[bh][d][kt*128..+127]
        #pragma unroll
        for (int c = 0; c < 4; ++c) {
            const int i = wave*4 + c;
            const int d = i*4 + (lane >> 4);
            const int tl = (lane & 15) * 8;
            async_copy16(Vt + i*512 + lane*8,
                         VT + hbase + (size_t)d * TT + kt*128 + tl);
        }
        asm volatile("s_waitcnt vmcnt(0)" ::: "memory");
        __syncthreads();

        // S^T = K Q^T : rows k (128), cols q (wave's 16)
        f32x4 s[8] = {};
        #pragma unroll
        for (int kc2 = 0; kc2 < 2; ++kc2) {
            bf16x8 bq = qreg[kc2];
            #pragma unroll
            for (int nt = 0; nt < 8; ++nt) {
                bf16x8 ak = *(const bf16x8*)(Ks + (nt*16 + l16)*64 + kc2*32 + quad*8);
                s[nt] = __builtin_amdgcn_mfma_f32_16x16x32_bf16(ak, bq, s[nt], 0, 0, 0);
            }
        }

        // causal mask: only the last KV tile straddles the diagonal
        if (kt == nkt - 1) {
            const int kq = kt*128 + quad*4;
            #pragma unroll
            for (int nt = 0; nt < 8; ++nt)
                #pragma unroll
                for (int r = 0; r < 4; ++r)
                    if (kq + nt*16 + r > qg) s[nt][r] = -1e30f;
        }

        // online softmax (per-lane state, q = l16)
        float mloc = -1e30f;
        #pragma unroll
        for (int nt = 0; nt < 8; ++nt)
            #pragma unroll
            for (int r = 0; r < 4; ++r)
                mloc = fmaxf(mloc, s[nt][r]);
        mloc = fmaxf(mloc, __shfl_xor(mloc, 16));
        mloc = fmaxf(mloc, __shfl_xor(mloc, 32));
        const float mnew = fmaxf(mst, mloc);
        const float alpha = exp2f((mst - mnew) * LOG2E);
        const float mc = mnew * LOG2E;
        mst = mnew;

        float rsum = 0.f;
        uint2 pck[8];
        #pragma unroll
        for (int nt = 0; nt < 8; ++nt) {
            const float p0 = exp2f(s[nt][0]*LOG2E - mc);
            const float p1 = exp2f(s[nt][1]*LOG2E - mc);
            const float p2 = exp2f(s[nt][2]*LOG2E - mc);
            const float p3 = exp2f(s[nt][3]*LOG2E - mc);
            rsum += (p0 + p1) + (p2 + p3);
            pck[nt].x = pack2bf(p0, p1);
            pck[nt].y = pack2bf(p2, p3);
        }
        rsum += __shfl_xor(rsum, 16);
        rsum += __shfl_xor(rsum, 32);
        lst = lst * alpha + rsum;

        // P[q][k] b64-packed (4 consecutive k = quad*4+r of tile nt)
        #pragma unroll
        for (int nt = 0; nt < 8; ++nt)
            *(uint2*)(&Ps[wave][l16*PSTR + nt*16 + quad*4]) = pck[nt];

        // rescale O by alpha (per q row = quad*4+r)
        float af[4];
        #pragma unroll
        for (int r = 0; r < 4; ++r) af[r] = __shfl(alpha, quad*4 + r);
        #pragma unroll
        for (int dt = 0; dt < 4; ++dt)
            #pragma unroll
            for (int r = 0; r < 4; ++r)
                oacc[dt][r] *= af[r];

        // O += P V  (A = P[q][k], B = Vt[d][k-slice])
        #pragma unroll
        for (int kc = 0; kc < 4; ++kc) {
            bf16x8 ap = *(const bf16x8*)(&Ps[wave][l16*PSTR + kc*32 + quad*8]);
            #pragma unroll
            for (int dt = 0; dt < 4; ++dt) {
                bf16x8 bv = *(const bf16x8*)(Vt + (dt*16 + l16)*128 + kc*32 + quad*8);
                oacc[dt] = __builtin_amdgcn_mfma_f32_16x16x32_bf16(ap, bv, oacc[dt], 0, 0, 0);
            }
        }
    }

    // epilogue: O/l -> Odup (4096 x 1536, dup cols packed as one uint store)
    const float linv = 1.0f / lst;
    float lr[4];
    #pragma unroll
    for (int r = 0; r < 4; ++r) lr[r] = __shfl(linv, quad*4 + r);
    const int b = bh / NHEADS, h = bh % NHEADS;
    #pragma unroll
    for (int r = 0; r < 4; ++r) {
        const int m = b * TT + qt*64 + wave*16 + quad*4 + r;
        #pragma unroll
        for (int dt = 0; dt < 4; ++dt) {
            const unsigned int ob = f2bf(oacc[dt][r] * lr[r]);
            const size_t o0 = (size_t)m * KSPLIT + (size_t)(h*HEAD + dt*16 + l16) * 2;
            *(unsigned int*)(&Odup[o0]) = ob * 0x10001u;
        }
    }
}

// ---------------------------------------------------------------------------
extern "C" void kernel_launch(void* const* d_in, const int* in_sizes, int n_in,
                              void* d_out, int out_size, void* d_ws, size_t ws_size,
                              hipStream_t stream) {
    const float* x  = (const float*)d_in[0];
    const float* W1 = (const float*)d_in[1];
    const float* b1 = (const float*)d_in[2];
    const float* W2 = (const float*)d_in[3];
    const float* b2 = (const float*)d_in[4];
    float* out = (float*)d_out;

    unsigned short* ws = (unsigned short*)d_ws;
    unsigned short* xdup = ws;                                  // 4096*1536
    unsigned short* w1s  = xdup + (size_t)MROWS * KSPLIT;       // 2304*1536
    unsigned short* w2s  = w1s + (size_t)F3 * KSPLIT;           // 768*1536
    unsigned short* Qb   = w2s + (size_t)D_MODEL * KSPLIT;      // 24*2048*64
    unsigned short* Kb   = Qb + (size_t)BB*NHEADS*TT*HEAD;
    unsigned short* Vb   = Kb + (size_t)BB*NHEADS*TT*HEAD;
    unsigned short* Odup = Vb + (size_t)BB*NHEADS*TT*HEAD;      // 4096*1536
    // VT aliases xdup: xdup is dead after gemm1, vtrans runs after gemm1.
    unsigned short* VT   = xdup;

    dup_act<<<(MROWS*D_MODEL + 255)/256, 256, 0, stream>>>(x, xdup, MROWS*D_MODEL);
    split_w<<<(F3*D_MODEL + 255)/256, 256, 0, stream>>>(W1, w1s, F3*D_MODEL);
    split_w<<<(D_MODEL*D_MODEL + 255)/256, 256, 0, stream>>>(W2, w2s, D_MODEL*D_MODEL);

    gemm_bt<0><<<dim3(MROWS/128, F3/128), 256, 0, stream>>>(
        xdup, w1s, b1, KSPLIT, nullptr, Qb, Kb, Vb);

    vtrans<<<dim3(TT/64, BB*NHEADS), 256, 0, stream>>>(Vb, VT);

    attn<<<dim3(TT/64, BB*NHEADS), 256, 0, stream>>>(Qb, Kb, VT, Odup);

    gemm_bt<1><<<dim3(MROWS/128, D_MODEL/128), 256, 0, stream>>>(
        Odup, w2s, b2, KSPLIT, out, nullptr, nullptr, nullptr);
}